// Round 1
// baseline (340.778 us; speedup 1.0000x reference)
//
#include <hip/hip_runtime.h>
#include <math.h>

#define COL 14
#define NJ 23
#define BATCH 4096
#define NJOINT (BATCH * NJ)              // 94208
#define RADIUS 4
#define BLOCKS 1024
#define THREADS 256
#define WAVES_TOTAL (BLOCKS * (THREADS / 64))   // 4096
#define JOINTS_PER_WAVE (NJOINT / WAVES_TOTAL)  // 23

__global__ __launch_bounds__(THREADS) void msq3d_kernel(
    const float* __restrict__ o,
    const float* __restrict__ h,
    const float* __restrict__ t,
    const int*   __restrict__ v,
    float* __restrict__ out)
{
    __shared__ float sM[COL][COL];          // M[row][col]
    __shared__ float sColMin[COL], sColMax[COL];
    __shared__ float sWaveSum[THREADS / 64];

    const int tid = threadIdx.x;

    // ---- build Gaussian matrix M once per block (matches scipy reflect) ----
    if (tid < COL * COL) {
        // weights in double to match numpy, then cast
        double wd[2 * RADIUS + 1];
        double wsum = 0.0;
        #pragma unroll
        for (int k = 0; k <= 2 * RADIUS; ++k) {
            double xx = (double)(k - RADIUS);
            wd[k] = exp(-0.5 * xx * xx);
            wsum += wd[k];
        }
        const int outr = tid / COL, ic = tid % COL;
        float acc = 0.0f;
        #pragma unroll
        for (int k = -RADIUS; k <= RADIUS; ++k) {
            int ii = (outr + k) % (2 * COL);
            if (ii < 0) ii += 2 * COL;
            if (ii >= COL) ii = 2 * COL - 1 - ii;
            if (ii == ic) acc += (float)(wd[k + RADIUS] / wsum);
        }
        sM[outr][ic] = acc;
    }
    __syncthreads();
    if (tid < COL) {
        float mn = sM[0][tid], mx = mn;
        for (int r = 1; r < COL; ++r) {
            float x = sM[r][tid];
            mn = fminf(mn, x);
            mx = fmaxf(mx, x);
        }
        sColMin[tid] = mn;
        sColMax[tid] = mx;
    }
    __syncthreads();

    const int lane = tid & 63;
    const int wave_in_blk = tid >> 6;
    const int gwave = blockIdx.x * (THREADS / 64) + wave_in_blk;
    const float scale = 1.0f / (float)COL;

    float accD = 0.0f;   // d1 elements on all lanes; d2 folded in on lane 0

    const int jbase = gwave * JOINTS_PER_WAVE;
    for (int jj = 0; jj < JOINTS_PER_WAVE; ++jj) {
        const int joint = jbase + jj;        // 0 .. NJOINT-1
        const int b = joint / NJ;
        const int j = joint - b * NJ;

        // wave-uniform loads (HW broadcasts a single request)
        const float t0 = t[joint * 3 + 0];
        const float t1 = t[joint * 3 + 1];
        const float t2 = t[joint * 3 + 2];
        const int   v0 = v[joint * 2 + 0];

        const float tx = t0 * (float)COL;
        const float ty = t1 * (float)COL;
        const int xi = (int)truncf(tx);
        const int yi = (int)truncf(ty);
        const bool in_range = (xi >= 0) && (xi <= COL - 1) && (yi >= 0) && (yi <= COL - 1);
        const bool mask = (v0 == 1) && in_range;
        const int xc = min(max(xi, 0), COL - 1);
        const int yc = min(max(yi, 0), COL - 1);

        // nonneg outer product: map-min = colmin*colmin, map-max = colmax*colmax (bit-exact)
        const float mn = sColMin[yc] * sColMin[xc];
        const float mx = sColMax[yc] * sColMax[xc];
        const float inv = 1.0f / (mx - mn);
        const float fm = mask ? 1.0f : 0.0f;

        const float* hb = h + (size_t)joint * (COL * COL);
        float bestv = -INFINITY;
        int besti = 0;

        #pragma unroll
        for (int pass = 0; pass < 4; ++pass) {
            int p = pass * 64 + lane;
            if (p < COL * COL) {
                float hv = hb[p];
                if (hv > bestv) { bestv = hv; besti = p; }   // first-occurrence argmax
                int r = p / COL;
                int c = p - r * COL;
                float ttv = fm * ((sM[r][yc] * sM[c][xc]) - mn) * inv;
                float d = hv - ttv;
                accD += d * d;
            }
        }

        // wave argmax reduction (64-lane, first-occurrence tie-break)
        #pragma unroll
        for (int off = 32; off > 0; off >>= 1) {
            float ov = __shfl_down(bestv, off, 64);
            int   oi = __shfl_down(besti, off, 64);
            if (ov > bestv || (ov == bestv && oi < besti)) { bestv = ov; besti = oi; }
        }

        if (lane == 0) {
            const int y = besti / COL;
            const int x = besti - y * COL;
            const size_t ob = (((size_t)b * (3 * NJ) + j) * COL + y) * COL + x;
            const float o0 = o[ob];
            const float o1 = o[ob + (size_t)NJ * COL * COL];
            const float o2 = o[ob + (size_t)(2 * NJ) * COL * COL];
            const float px = o0 + (float)x * scale;
            const float py = o1 + (float)y * scale;
            const float dx = px - t0;
            const float dy = py - t1;
            const float dz = o2 - t2;
            accD += dx * dx + dy * dy + dz * dz;
        }
    }

    // wave sum reduction
    #pragma unroll
    for (int off = 32; off > 0; off >>= 1)
        accD += __shfl_down(accD, off, 64);
    if (lane == 0) sWaveSum[wave_in_blk] = accD;
    __syncthreads();
    if (tid == 0) {
        float s = 0.0f;
        #pragma unroll
        for (int w = 0; w < THREADS / 64; ++w) s += sWaveSum[w];
        atomicAdd(out, s * (1.0f / (float)NJ));
    }
}

extern "C" void kernel_launch(void* const* d_in, const int* in_sizes, int n_in,
                              void* d_out, int out_size, void* d_ws, size_t ws_size,
                              hipStream_t stream) {
    const float* o = (const float*)d_in[0];
    const float* h = (const float*)d_in[1];
    const float* t = (const float*)d_in[2];
    const int*   v = (const int*)d_in[3];
    float* out = (float*)d_out;

    hipMemsetAsync(d_out, 0, sizeof(float), stream);
    msq3d_kernel<<<BLOCKS, THREADS, 0, stream>>>(o, h, t, v, out);
}

// Round 2
// 326.884 us; speedup vs baseline: 1.0425x; 1.0425x over previous
//
#include <hip/hip_runtime.h>
#include <math.h>

#define COL 14
#define NJ 23
#define BATCH 4096
#define NJOINT (BATCH * NJ)              // 94208
#define RADIUS 4
#define THREADS 256
#define BLOCKS 2048
#define WAVES_TOTAL (BLOCKS * (THREADS / 64))   // 8192 waves, grid-stride over joints

__global__ __launch_bounds__(THREADS) void msq3d_kernel(
    const float* __restrict__ o,
    const float* __restrict__ h,
    const float* __restrict__ t,
    const int*   __restrict__ v,
    float* __restrict__ out)
{
    __shared__ float sM[COL * COL];         // M[row*COL + col]
    __shared__ float sColMin[COL], sColMax[COL];
    __shared__ float sWaveSum[THREADS / 64];

    const int tid = threadIdx.x;

    // ---- build Gaussian matrix M once per block (matches scipy reflect) ----
    if (tid < COL * COL) {
        double wd[2 * RADIUS + 1];
        double wsum = 0.0;
        #pragma unroll
        for (int k = 0; k <= 2 * RADIUS; ++k) {
            double xx = (double)(k - RADIUS);
            wd[k] = exp(-0.5 * xx * xx);
            wsum += wd[k];
        }
        const int outr = tid / COL, ic = tid % COL;
        float acc = 0.0f;
        #pragma unroll
        for (int k = -RADIUS; k <= RADIUS; ++k) {
            int ii = (outr + k) % (2 * COL);
            if (ii < 0) ii += 2 * COL;
            if (ii >= COL) ii = 2 * COL - 1 - ii;
            if (ii == ic) acc += (float)(wd[k + RADIUS] / wsum);
        }
        sM[outr * COL + ic] = acc;
    }
    __syncthreads();
    if (tid < COL) {
        float mn = sM[tid], mx = mn;
        for (int r = 1; r < COL; ++r) {
            float x = sM[r * COL + tid];
            mn = fminf(mn, x);
            mx = fmaxf(mx, x);
        }
        sColMin[tid] = mn;
        sColMax[tid] = mx;
    }
    __syncthreads();

    const int lane = tid & 63;
    const int wave_in_blk = tid >> 6;
    const int gwave = blockIdx.x * (THREADS / 64) + wave_in_blk;
    const float scale = 1.0f / (float)COL;

    // per-lane static geometry: lane handles elements q0..q0+3 of each 196-elem map
    const bool act = (lane < 49);           // 49 * 4 = 196
    const int q0 = lane * 4;
    int rk[4], ck[4];
    #pragma unroll
    for (int k = 0; k < 4; ++k) {
        int q = q0 + k;
        if (q > COL * COL - 1) q = COL * COL - 1;   // clamp (inactive lanes; avoid OOB LDS addr)
        rk[k] = q / COL;
        ck[k] = q - rk[k] * COL;
    }

    float accD = 0.0f;   // d1 partial on all lanes; d2 folded in on lane 0

    for (int joint = gwave; joint < NJOINT; joint += WAVES_TOTAL) {
        const int b = joint / NJ;
        const int j = joint - b * NJ;

        // wave-uniform loads -> scalar loads
        const float t0 = t[joint * 3 + 0];
        const float t1 = t[joint * 3 + 1];
        const float t2 = t[joint * 3 + 2];
        const int   v0 = v[joint * 2 + 0];

        const int xi = (int)truncf(t0 * (float)COL);
        const int yi = (int)truncf(t1 * (float)COL);
        const bool in_range = (xi >= 0) && (xi <= COL - 1) && (yi >= 0) && (yi <= COL - 1);
        const bool mask = (v0 == 1) && in_range;
        const int xc = min(max(xi, 0), COL - 1);
        const int yc = min(max(yi, 0), COL - 1);

        // single dwordx4 load per joint: lanes 0..48 cover all 196 floats
        const float4* hb4 = (const float4*)(h + (size_t)joint * (COL * COL));
        float4 hv4 = make_float4(0.f, 0.f, 0.f, 0.f);
        if (act) hv4 = hb4[lane];
        const float hv[4] = {hv4.x, hv4.y, hv4.z, hv4.w};

        // local argmax over this lane's 4 elements (first occurrence)
        float lv = -INFINITY;
        int   lq = 0;
        if (act) {
            #pragma unroll
            for (int k = 0; k < 4; ++k) {
                if (hv[k] > lv) { lv = hv[k]; lq = q0 + k; }
            }
        }

        // d1 accumulation (wave-uniform branch on mask: ~50% skip the tt math)
        if (mask) {
            const float mn  = sColMin[yc] * sColMin[xc];
            const float mx  = sColMax[yc] * sColMax[xc];
            const float inv = 1.0f / (mx - mn);
            if (act) {
                #pragma unroll
                for (int k = 0; k < 4; ++k) {
                    float ttv = (sM[rk[k] * COL + yc] * sM[ck[k] * COL + xc] - mn) * inv;
                    float d = hv[k] - ttv;
                    accD += d * d;
                }
            }
        } else if (act) {
            #pragma unroll
            for (int k = 0; k < 4; ++k)
                accD += hv[k] * hv[k];
        }

        // wave argmax: value-only butterfly max, then ballot picks lowest lane (== first occurrence)
        float wmax = lv;
        #pragma unroll
        for (int off = 1; off < 64; off <<= 1)
            wmax = fmaxf(wmax, __shfl_xor(wmax, off, 64));
        unsigned long long mb = __ballot(act && (lv == wmax));
        const int src = (int)(__ffsll((long long)mb) - 1);
        const int besti = __shfl(lq, src, 64);

        if (lane == 0) {
            const int y = besti / COL;
            const int x = besti - y * COL;
            const size_t ob = (((size_t)b * (3 * NJ) + j) * COL + y) * COL + x;
            const float o0 = o[ob];
            const float o1 = o[ob + (size_t)NJ * COL * COL];
            const float o2 = o[ob + (size_t)(2 * NJ) * COL * COL];
            const float dx = (o0 + (float)x * scale) - t0;
            const float dy = (o1 + (float)y * scale) - t1;
            const float dz = o2 - t2;
            accD += dx * dx + dy * dy + dz * dz;
        }
    }

    // wave sum reduction
    #pragma unroll
    for (int off = 32; off > 0; off >>= 1)
        accD += __shfl_down(accD, off, 64);
    if (lane == 0) sWaveSum[wave_in_blk] = accD;
    __syncthreads();
    if (tid == 0) {
        float s = 0.0f;
        #pragma unroll
        for (int w = 0; w < THREADS / 64; ++w) s += sWaveSum[w];
        atomicAdd(out, s * (1.0f / (float)NJ));
    }
}

extern "C" void kernel_launch(void* const* d_in, const int* in_sizes, int n_in,
                              void* d_out, int out_size, void* d_ws, size_t ws_size,
                              hipStream_t stream) {
    const float* o = (const float*)d_in[0];
    const float* h = (const float*)d_in[1];
    const float* t = (const float*)d_in[2];
    const int*   v = (const int*)d_in[3];
    float* out = (float*)d_out;

    hipMemsetAsync(d_out, 0, sizeof(float), stream);
    msq3d_kernel<<<BLOCKS, THREADS, 0, stream>>>(o, h, t, v, out);
}